// Round 12
// baseline (117.787 us; speedup 1.0000x reference)
//
#include <hip/hip_runtime.h>
#include <math.h>

#define B 8
#define T 128
#define NKEY 127   // t-1
#define NPAD 128   // padded key count (score row 127 forced to prob 0)
#define KDIM 64    // Q_DIM == KV_DIM
#define NH 4       // heads
#define CH 256     // NH*KDIM output channels
#define LAM 2.885390081777927f   // 2*log2(e): e^{2x} = exp2(LAM*x)

typedef _Float16 half8v __attribute__((ext_vector_type(8)));  // 8 fp16 (4 VGPRs)
typedef _Float16 half4v __attribute__((ext_vector_type(4)));  // 4 fp16 (b64)
typedef float floatx4 __attribute__((ext_vector_type(4)));    // MFMA C/D

// 8x float -> fp16 RNE. Verified (R15/R17/R18 pass): absmax <= 9.77e-4.
__device__ __forceinline__ half8v cvt8_rne(const float4& a, const float4& b) {
    half8v h;
    h[0] = (_Float16)a.x; h[1] = (_Float16)a.y;
    h[2] = (_Float16)a.z; h[3] = (_Float16)a.w;
    h[4] = (_Float16)b.x; h[5] = (_Float16)b.y;
    h[6] = (_Float16)b.z; h[7] = (_Float16)b.w;
    return h;
}

// R19 = R18 (PASSED, ~114.5us harness) + ONE delta: T14 async-stage split.
// R18's epilogue fold was neutral -> the wall is exposed memory latency, not
// VALU issue count. Here the 8 kv dwordx4 loads (HBM-cold: the harness's
// 262MB inter-iteration fill evicts L2/L3; FETCH=25.5MB/dispatch) are ISSUED
// FIRST into registers; the Wq dot, A-frag loads+cvt, and ws prep (~1500cy of
// independent work) run while they fly; cvt+frag/kvT writes happen last.
// VGPR rises to ~96-112 (held kv regs) -- still under the (256,2) 128 cap,
// 16 waves/CU and 4 blocks/CU (LDS 37376) unchanged.
// Everything else byte-identical to R18.
__global__ __launch_bounds__(256, 2)
void attn_kernel(const float* __restrict__ q_x,   // (B,T,64)
                 const float* __restrict__ kv_x,  // (B,T,127,64)
                 const float* __restrict__ Wk,    // (256,64)
                 const float* __restrict__ Wq,    // (256,64)
                 const float* __restrict__ Wv,    // (256,64)
                 const float* __restrict__ bias,  // (64,)
                 const float* __restrict__ Ws,    // (1,64)
                 const float* __restrict__ bs,    // (1,) -- cancels in softmax
                 float* __restrict__ out)         // (B,T,256)
{
    __shared__ __align__(16) _Float16 frag[16][64][8];   // 16 KB: fp16 B-frags
    __shared__ __align__(16) _Float16 kvT[64][132];      // 16.5 KB: fp16 kv^T
    __shared__ float qb_lds[CH];                         // 1 KB: LAM*(query+bias)
    __shared__ float p_lds[NH][NPAD];                    // 2 KB: scores then probs
    __shared__ __align__(16) float wkv_lds[NH][KDIM];    // 1 KB -> total 37376 B

    const int bt   = blockIdx.x;
    const int tid  = threadIdx.x;
    const int h    = tid >> 6;    // wave index == head index
    const int lane = tid & 63;
    const int col  = lane & 15;   // MFMA n/m lane index
    const int quad = lane >> 4;   // MFMA k-group / row-group

    const float* __restrict__ kvg = kv_x + (size_t)bt * NKEY * KDIM;

    // ---- (1) ISSUE kv loads into registers (latency parks under (2)) ----
    float4 ka[4], kb[4];
    #pragma unroll
    for (int w = 0; w < 4; ++w) {
        const int chunk = w * 4 + h;          // each wave does 4 chunks
        const int nt = chunk >> 1, ks = chunk & 1;
        const int n  = nt * 16 + (lane & 15);
        const int k0 = ks * 32 + (lane >> 4) * 8;
        ka[w] = make_float4(0.f, 0.f, 0.f, 0.f);
        kb[w] = make_float4(0.f, 0.f, 0.f, 0.f);
        if (n < NKEY) {
            const float* p = kvg + (size_t)n * KDIM + k0;
            ka[w] = *(const float4*)p;
            kb[w] = *(const float4*)(p + 4);
        }
    }

    // ---- (2a) query_j + bias -> qb_lds[channel], prescaled by LAM ----
    {
        const float4* Wq4 = (const float4*)(Wq + (size_t)tid * KDIM);
        const float4* q4g = (const float4*)(q_x + (size_t)bt * KDIM);
        float4 qa = {0.f, 0.f, 0.f, 0.f};
        #pragma unroll
        for (int i = 0; i < 16; ++i) {
            float4 w = Wq4[i];
            float4 q4 = q4g[i];
            qa.x = fmaf(q4.x, w.x, qa.x);
            qa.y = fmaf(q4.y, w.y, qa.y);
            qa.z = fmaf(q4.z, w.z, qa.z);
            qa.w = fmaf(q4.w, w.w, qa.w);
        }
        qb_lds[tid] = ((qa.x + qa.y) + (qa.z + qa.w) + bias[tid & 63]) * LAM;
    }

    // ---- (2b) A-fragments: LAM*Wk rows of this head, fp16 RNE ----
    // lane holds LAM*Wk[h*64 + jt*16 + col][ks*32 + quad*8 + j]
    half8v ah[4][2];
    #pragma unroll
    for (int jt = 0; jt < 4; ++jt)
        #pragma unroll
        for (int ks = 0; ks < 2; ++ks) {
            const float* wrow = Wk + (size_t)(h * 64 + jt * 16 + col) * KDIM
                                   + ks * 32 + quad * 8;
            float4 a = *(const float4*)wrow;
            float4 b = *(const float4*)(wrow + 4);
            a.x *= LAM; a.y *= LAM; a.z *= LAM; a.w *= LAM;
            b.x *= LAM; b.y *= LAM; b.z *= LAM; b.w *= LAM;
            ah[jt][ks] = cvt8_rne(a, b);
        }

    // ---- (2c) folded ws + hoisted wssum (depends only on Ws: pre-barrier) ----
    float ws2[4][4];
    float wssum = 0.f;
    #pragma unroll
    for (int jt = 0; jt < 4; ++jt)
        #pragma unroll
        for (int r = 0; r < 4; ++r) {
            float w = Ws[jt * 16 + quad * 4 + r];
            wssum += w;
            ws2[jt][r] = -2.f * w;
        }

    // ---- (3) kv cvt + frag/kvT writes (loads have landed by now) ----
    // frag: chunk*1024 + lane*16, lane-linear, 0 conflicts.
    // kvT transpose: rows k0..k0+7, col n; zeros land in column 127.
    #pragma unroll
    for (int w = 0; w < 4; ++w) {
        const int chunk = w * 4 + h;
        const int n  = (chunk >> 1) * 16 + (lane & 15);
        const int k0 = (chunk & 1) * 32 + (lane >> 4) * 8;
        half8v hv = cvt8_rne(ka[w], kb[w]);
        *(half8v*)&frag[chunk][lane][0] = hv;
        #pragma unroll
        for (int j = 0; j < 8; ++j)
            kvT[k0 + j][n] = hv[j];
    }

    __syncthreads();   // barrier: frags + kvT + qb ready

    // ---- qb as MFMA C-init (R10/R18-verified) ----
    // C/D layout: col = lane&15 = n, row = quad*4 + r = j in jt-tile.
    floatx4 qb4[4];
    #pragma unroll
    for (int jt = 0; jt < 4; ++jt)
        qb4[jt] = *(const floatx4*)&qb_lds[h * 64 + jt * 16 + quad * 4];

    // ---- scores: 8 n-tiles of 16 keys; single-pass fp16 MFMA ----
    #pragma unroll
    for (int nt = 0; nt < 8; ++nt) {
        half8v b0 = *(const half8v*)&frag[nt * 2 + 0][lane][0];
        half8v b1 = *(const half8v*)&frag[nt * 2 + 1][lane][0];

        floatx4 acc[4];
        #pragma unroll
        for (int jt = 0; jt < 4; ++jt) {
            floatx4 c = qb4[jt];   // C-init = LAM*(query+bias); keys add on
            c = __builtin_amdgcn_mfma_f32_16x16x32_f16(ah[jt][0], b0, c, 0, 0, 0);
            c = __builtin_amdgcn_mfma_f32_16x16x32_f16(ah[jt][1], b1, c, 0, 0, 0);
            acc[jt] = c;
        }

        // epilogue: score[n] = wssum + sum_j ws2[j] * 1/(exp2(c)+1)
        //   (ws*tanh(x) = ws - 2ws/(e^{2x}+1), c = LAM*x, exp2(c) = e^{2x})
        float partial = wssum;
        #pragma unroll
        for (int jt = 0; jt < 4; ++jt)
            #pragma unroll
            for (int r = 0; r < 4; ++r) {
                float e  = exp2f(acc[jt][r]);               // v_exp_f32
                float rc = __builtin_amdgcn_rcpf(e + 1.f);
                partial  = fmaf(ws2[jt][r], rc, partial);
            }
        partial += __shfl_xor(partial, 16, 64);   // reduce across quads (same col)
        partial += __shfl_xor(partial, 32, 64);
        if (lane < 16) p_lds[h][nt * 16 + lane] = partial;
    }
    // no barrier: wave h is sole writer+reader of p_lds[h][*] (DS in-order)

    // ---- softmax over the 127 real keys (2 scores per lane) ----
    float invl;
    {
        float s_a = p_lds[h][lane];
        float s_b = p_lds[h][64 + lane];
        if (lane == 63) s_b = -1e30f;          // mask pad row 127
        float mx = fmaxf(s_a, s_b);
        #pragma unroll
        for (int off = 32; off > 0; off >>= 1)
            mx = fmaxf(mx, __shfl_xor(mx, off, 64));
        float pa = __expf(s_a - mx);
        float pb = __expf(s_b - mx);           // lane 63 -> 0
        float ls = pa + pb;
        #pragma unroll
        for (int off = 32; off > 0; off >>= 1)
            ls += __shfl_xor(ls, off, 64);
        invl = 1.f / ls;
        p_lds[h][lane]      = pa;              // unnormalized probs
        p_lds[h][64 + lane] = pb;              // p_lds[h][127] = 0 masks pad
    }

    // ---- Phase B: wkv[h][k=lane] = (sum_n p[n] * kvT[k][n]) / l, all LDS ----
    // 32 linear ds_read_b64 of row k (stride 264 B == 2 dw mod 32: lanes
    // k,k+16 alias 2-way = free; k,k+8 differ by 16 banks). Probs: float4
    // uniform broadcast. Column 127 holds zeros; p[127] = 0 too.
    {
        const _Float16* kvr = &kvT[lane][0];
        float w0 = 0.f, w1 = 0.f, w2 = 0.f, w3 = 0.f;
        #pragma unroll 8
        for (int s = 0; s < 32; ++s) {
            half4v v  = *(const half4v*)(kvr + s * 4);
            float4 p4 = *(const float4*)&p_lds[h][s * 4];    // uniform broadcast
            w0 = fmaf(p4.x, (float)v[0], w0);
            w1 = fmaf(p4.y, (float)v[1], w1);
            w2 = fmaf(p4.z, (float)v[2], w2);
            w3 = fmaf(p4.w, (float)v[3], w3);
        }
        wkv_lds[h][lane] = ((w0 + w1) + (w2 + w3)) * invl;
    }
    // no barrier: wkv_lds[h] written and read only by wave h (DS in-order)

    // ---- Phase C: out[j] = wkv[h,:] . Wv[j,:] ----
    {
        const float4* Wv4 = (const float4*)(Wv + (size_t)tid * KDIM);
        const float4* wv_row = (const float4*)wkv_lds[h];
        float4 oa = {0.f, 0.f, 0.f, 0.f};
        #pragma unroll
        for (int i = 0; i < 16; ++i) {
            float4 w = Wv4[i];
            float4 c = wv_row[i];                        // broadcast
            oa.x = fmaf(c.x, w.x, oa.x);
            oa.y = fmaf(c.y, w.y, oa.y);
            oa.z = fmaf(c.z, w.z, oa.z);
            oa.w = fmaf(c.w, w.w, oa.w);
        }
        out[(size_t)bt * CH + tid] = (oa.x + oa.y) + (oa.z + oa.w);
    }
}

extern "C" void kernel_launch(void* const* d_in, const int* in_sizes, int n_in,
                              void* d_out, int out_size, void* d_ws, size_t ws_size,
                              hipStream_t stream) {
    const float* q_x  = (const float*)d_in[0];
    const float* kv_x = (const float*)d_in[1];
    const float* Wk   = (const float*)d_in[2];
    const float* Wq   = (const float*)d_in[3];
    const float* Wv   = (const float*)d_in[4];
    const float* bias = (const float*)d_in[5];
    const float* Ws   = (const float*)d_in[6];
    const float* bs   = (const float*)d_in[7];
    float* out = (float*)d_out;

    attn_kernel<<<dim3(B * T), dim3(256), 0, stream>>>(
        q_x, kv_x, Wk, Wq, Wv, bias, Ws, bs, out);
}

// Round 13
// 114.277 us; speedup vs baseline: 1.0307x; 1.0307x over previous
//
#include <hip/hip_runtime.h>
#include <math.h>

#define B 8
#define T 128
#define NKEY 127   // t-1
#define NPAD 128   // padded key count (score row 127 forced to prob 0)
#define KDIM 64    // Q_DIM == KV_DIM
#define NH 4       // heads
#define CH 256     // NH*KDIM output channels
#define LAM 2.885390081777927f   // 2*log2(e): e^{2x} = exp2(LAM*x)

typedef _Float16 half8v __attribute__((ext_vector_type(8)));  // 8 fp16 (4 VGPRs)
typedef _Float16 half4v __attribute__((ext_vector_type(4)));  // 4 fp16 (b64)
typedef float floatx4 __attribute__((ext_vector_type(4)));    // MFMA C/D

// 8x float -> fp16 RNE. Verified (R15/R17/R18 pass): absmax <= 9.77e-4.
__device__ __forceinline__ half8v cvt8_rne(const float4& a, const float4& b) {
    half8v h;
    h[0] = (_Float16)a.x; h[1] = (_Float16)a.y;
    h[2] = (_Float16)a.z; h[3] = (_Float16)a.w;
    h[4] = (_Float16)b.x; h[5] = (_Float16)b.y;
    h[6] = (_Float16)b.z; h[7] = (_Float16)b.w;
    return h;
}

// R20 = R18 (PASSED) + ONE restructure: batched-frag score loop.
// Falsified so far: occupancy (R9/R10/R16), epilogue VALU count (R18),
// staging latency (R19), Phase-B global latency (R17, the one win). Remaining
// suspect: VGPR_Count pinned at 48-64 across all variants -- the score loop's
// steady live set (ah 32 + qb4 16 + ws2 16) fills the allocation, so the
// compiler CANNOT pipeline the 8-nt loop: every nt pays ds_read + MFMA
// latency exposed. VGPR up to 128 is free here (grid caps at 16 waves/CU;
// VGPR occupancy step is at 128). Fix: 2 half-passes; each issues its 8
// ds_read_b128 up-front into 32 VGPR of fragments, then computes 4 nt tiles
// -- LDS latency paid once per half, explicit ILP across 4 independent tiles.
// Same ops/order per value; in-loop shfl reduce kept (deferred-reduce banned).
__global__ __launch_bounds__(256, 2)
void attn_kernel(const float* __restrict__ q_x,   // (B,T,64)
                 const float* __restrict__ kv_x,  // (B,T,127,64)
                 const float* __restrict__ Wk,    // (256,64)
                 const float* __restrict__ Wq,    // (256,64)
                 const float* __restrict__ Wv,    // (256,64)
                 const float* __restrict__ bias,  // (64,)
                 const float* __restrict__ Ws,    // (1,64)
                 const float* __restrict__ bs,    // (1,) -- cancels in softmax
                 float* __restrict__ out)         // (B,T,256)
{
    __shared__ __align__(16) _Float16 frag[16][64][8];   // 16 KB: fp16 B-frags
    __shared__ __align__(16) _Float16 kvT[64][132];      // 16.5 KB: fp16 kv^T
    __shared__ float qb_lds[CH];                         // 1 KB: LAM*(query+bias)
    __shared__ float p_lds[NH][NPAD];                    // 2 KB: scores then probs
    __shared__ __align__(16) float wkv_lds[NH][KDIM];    // 1 KB -> total 37376 B

    const int bt   = blockIdx.x;
    const int tid  = threadIdx.x;
    const int h    = tid >> 6;    // wave index == head index
    const int lane = tid & 63;
    const int col  = lane & 15;   // MFMA n/m lane index
    const int quad = lane >> 4;   // MFMA k-group / row-group

    const float* __restrict__ kvg = kv_x + (size_t)bt * NKEY * KDIM;

    // ---- convert kv (global) -> fragment-ordered fp16 LDS + fp16 kv^T ----
    // chunk = nt*2+ks; frag write addr = chunk*1024 + lane*16: lane-linear.
    // Fragment content: kv[nt*16 + (lane&15)][ks*32 + (lane>>4)*8 + j]
    #pragma unroll
    for (int w = 0; w < 4; ++w) {
        const int chunk = w * 4 + h;          // each wave does 4 chunks
        const int nt = chunk >> 1, ks = chunk & 1;
        const int n  = nt * 16 + (lane & 15);
        const int k0 = ks * 32 + (lane >> 4) * 8;
        float4 a = make_float4(0.f, 0.f, 0.f, 0.f);
        float4 b = make_float4(0.f, 0.f, 0.f, 0.f);
        if (n < NKEY) {
            const float* p = kvg + (size_t)n * KDIM + k0;
            a = *(const float4*)p;
            b = *(const float4*)(p + 4);
        }
        half8v hv = cvt8_rne(a, b);
        *(half8v*)&frag[chunk][lane][0] = hv;
        #pragma unroll
        for (int j = 0; j < 8; ++j)           // transpose: rows k0..k0+7, col n
            kvT[k0 + j][n] = hv[j];           // zeros land in column 127
    }

    // ---- query_j + bias -> qb_lds[channel], prescaled by LAM ----
    {
        const float4* Wq4 = (const float4*)(Wq + (size_t)tid * KDIM);
        const float4* q4g = (const float4*)(q_x + (size_t)bt * KDIM);
        float4 qa = {0.f, 0.f, 0.f, 0.f};
        #pragma unroll
        for (int i = 0; i < 16; ++i) {
            float4 w = Wq4[i];
            float4 q4 = q4g[i];
            qa.x = fmaf(q4.x, w.x, qa.x);
            qa.y = fmaf(q4.y, w.y, qa.y);
            qa.z = fmaf(q4.z, w.z, qa.z);
            qa.w = fmaf(q4.w, w.w, qa.w);
        }
        qb_lds[tid] = ((qa.x + qa.y) + (qa.z + qa.w) + bias[tid & 63]) * LAM;
    }

    // ---- A-fragments: LAM*Wk rows of this head, fp16 RNE ----
    // lane holds LAM*Wk[h*64 + jt*16 + col][ks*32 + quad*8 + j]
    half8v ah[4][2];
    #pragma unroll
    for (int jt = 0; jt < 4; ++jt)
        #pragma unroll
        for (int ks = 0; ks < 2; ++ks) {
            const float* wrow = Wk + (size_t)(h * 64 + jt * 16 + col) * KDIM
                                   + ks * 32 + quad * 8;
            float4 a = *(const float4*)wrow;
            float4 b = *(const float4*)(wrow + 4);
            a.x *= LAM; a.y *= LAM; a.z *= LAM; a.w *= LAM;
            b.x *= LAM; b.y *= LAM; b.z *= LAM; b.w *= LAM;
            ah[jt][ks] = cvt8_rne(a, b);
        }

    __syncthreads();   // barrier: frags + kvT + qb ready

    // ---- qb as MFMA C-init; folded ws; hoisted wssum (R18-verified) ----
    // C/D layout: col = lane&15 = n, row = quad*4 + r = j in jt-tile.
    floatx4 qb4[4];
    float   ws2[4][4];
    float   wssum = 0.f;
    #pragma unroll
    for (int jt = 0; jt < 4; ++jt) {
        qb4[jt] = *(const floatx4*)&qb_lds[h * 64 + jt * 16 + quad * 4];
        #pragma unroll
        for (int r = 0; r < 4; ++r) {
            float w = Ws[jt * 16 + quad * 4 + r];
            wssum += w;
            ws2[jt][r] = -2.f * w;
        }
    }

    // ---- scores: 2 half-passes; 8 ds_read_b128 issued up-front per half,
    //      then 4 nt tiles computed on pre-loaded frags (explicit ILP) ----
    #pragma unroll
    for (int hp = 0; hp < 2; ++hp) {
        half8v bf[8];
        #pragma unroll
        for (int i = 0; i < 8; ++i)
            bf[i] = *(const half8v*)&frag[hp * 8 + i][lane][0];

        #pragma unroll
        for (int t = 0; t < 4; ++t) {
            const int nt = hp * 4 + t;
            half8v b0 = bf[t * 2 + 0];
            half8v b1 = bf[t * 2 + 1];

            floatx4 acc[4];
            #pragma unroll
            for (int jt = 0; jt < 4; ++jt) {
                floatx4 c = qb4[jt];   // C-init = LAM*(query+bias); keys add on
                c = __builtin_amdgcn_mfma_f32_16x16x32_f16(ah[jt][0], b0, c, 0, 0, 0);
                c = __builtin_amdgcn_mfma_f32_16x16x32_f16(ah[jt][1], b1, c, 0, 0, 0);
                acc[jt] = c;
            }

            // epilogue: score[n] = wssum + sum_j ws2[j] / (exp2(c)+1)
            //   (ws*tanh(x) = ws - 2ws/(e^{2x}+1), c = LAM*x)
            float partial = wssum;
            #pragma unroll
            for (int jt = 0; jt < 4; ++jt)
                #pragma unroll
                for (int r = 0; r < 4; ++r) {
                    float e  = exp2f(acc[jt][r]);               // v_exp_f32
                    float rc = __builtin_amdgcn_rcpf(e + 1.f);
                    partial  = fmaf(ws2[jt][r], rc, partial);
                }
            partial += __shfl_xor(partial, 16, 64);   // reduce across quads
            partial += __shfl_xor(partial, 32, 64);
            if (lane < 16) p_lds[h][nt * 16 + lane] = partial;
        }
    }
    // no barrier: wave h is sole writer+reader of p_lds[h][*] (DS in-order)

    // ---- softmax over the 127 real keys (2 scores per lane) ----
    float invl;
    {
        float s_a = p_lds[h][lane];
        float s_b = p_lds[h][64 + lane];
        if (lane == 63) s_b = -1e30f;          // mask pad row 127
        float mx = fmaxf(s_a, s_b);
        #pragma unroll
        for (int off = 32; off > 0; off >>= 1)
            mx = fmaxf(mx, __shfl_xor(mx, off, 64));
        float pa = __expf(s_a - mx);
        float pb = __expf(s_b - mx);           // lane 63 -> 0
        float ls = pa + pb;
        #pragma unroll
        for (int off = 32; off > 0; off >>= 1)
            ls += __shfl_xor(ls, off, 64);
        invl = 1.f / ls;
        p_lds[h][lane]      = pa;              // unnormalized probs
        p_lds[h][64 + lane] = pb;              // p_lds[h][127] = 0 masks pad
    }

    // ---- Phase B: wkv[h][k=lane] = (sum_n p[n] * kvT[k][n]) / l, all LDS ----
    // 32 linear ds_read_b64 of row k (stride 264 B == 2 dw mod 32: lanes
    // k,k+16 alias 2-way = free; k,k+8 differ by 16 banks). Probs: float4
    // uniform broadcast. Column 127 holds zeros; p[127] = 0 too.
    {
        const _Float16* kvr = &kvT[lane][0];
        float w0 = 0.f, w1 = 0.f, w2 = 0.f, w3 = 0.f;
        #pragma unroll 8
        for (int s = 0; s < 32; ++s) {
            half4v v  = *(const half4v*)(kvr + s * 4);
            float4 p4 = *(const float4*)&p_lds[h][s * 4];    // uniform broadcast
            w0 = fmaf(p4.x, (float)v[0], w0);
            w1 = fmaf(p4.y, (float)v[1], w1);
            w2 = fmaf(p4.z, (float)v[2], w2);
            w3 = fmaf(p4.w, (float)v[3], w3);
        }
        wkv_lds[h][lane] = ((w0 + w1) + (w2 + w3)) * invl;
    }
    // no barrier: wkv_lds[h] written and read only by wave h (DS in-order)

    // ---- Phase C: out[j] = wkv[h,:] . Wv[j,:] ----
    {
        const float4* Wv4 = (const float4*)(Wv + (size_t)tid * KDIM);
        const float4* wv_row = (const float4*)wkv_lds[h];
        float4 oa = {0.f, 0.f, 0.f, 0.f};
        #pragma unroll
        for (int i = 0; i < 16; ++i) {
            float4 w = Wv4[i];
            float4 c = wv_row[i];                        // broadcast
            oa.x = fmaf(c.x, w.x, oa.x);
            oa.y = fmaf(c.y, w.y, oa.y);
            oa.z = fmaf(c.z, w.z, oa.z);
            oa.w = fmaf(c.w, w.w, oa.w);
        }
        out[(size_t)bt * CH + tid] = (oa.x + oa.y) + (oa.z + oa.w);
    }
}

extern "C" void kernel_launch(void* const* d_in, const int* in_sizes, int n_in,
                              void* d_out, int out_size, void* d_ws, size_t ws_size,
                              hipStream_t stream) {
    const float* q_x  = (const float*)d_in[0];
    const float* kv_x = (const float*)d_in[1];
    const float* Wk   = (const float*)d_in[2];
    const float* Wq   = (const float*)d_in[3];
    const float* Wv   = (const float*)d_in[4];
    const float* bias = (const float*)d_in[5];
    const float* Ws   = (const float*)d_in[6];
    const float* bs   = (const float*)d_in[7];
    float* out = (float*)d_out;

    attn_kernel<<<dim3(B * T), dim3(256), 0, stream>>>(
        q_x, kv_x, Wk, Wq, Wv, bias, Ws, bs, out);
}